// Round 10
// baseline (242.599 us; speedup 1.0000x reference)
//
#include <hip/hip_runtime.h>

#define T_STEPS 301
#define IN_DIM  40
#define LOG2E   1.44269504088896340736f

typedef __attribute__((ext_vector_type(8))) _Float16 f16x8;
typedef __attribute__((ext_vector_type(4))) float f32x4;
typedef unsigned short ushort_t;
typedef unsigned int uint_t;

__device__ __forceinline__ f16x8 cvt8h(const float4 a, const float4 b) {
  f16x8 r;
  r[0] = (_Float16)a.x; r[1] = (_Float16)a.y; r[2] = (_Float16)a.z; r[3] = (_Float16)a.w;
  r[4] = (_Float16)b.x; r[5] = (_Float16)b.y; r[6] = (_Float16)b.z; r[7] = (_Float16)b.w;
  return r;
}

// z pre-scaled by log2e (2*log2e for g-gate) -> exp2-based activations.
__device__ __forceinline__ float lstm_act(float zi, float zf, float zg, float zo, float& cc) {
  const float ig = __builtin_amdgcn_rcpf(1.0f + __builtin_amdgcn_exp2f(-zi));
  const float fg = __builtin_amdgcn_rcpf(1.0f + __builtin_amdgcn_exp2f(-zf));
  const float gg = 1.0f - 2.0f * __builtin_amdgcn_rcpf(1.0f + __builtin_amdgcn_exp2f(zg));
  const float og = __builtin_amdgcn_rcpf(1.0f + __builtin_amdgcn_exp2f(-zo));
  cc = fg * cc + ig * gg;
  const float tc = 1.0f - 2.0f * __builtin_amdgcn_rcpf(1.0f + __builtin_amdgcn_exp2f(cc * (2.0f * LOG2E)));
  return og * tc;
}

// 256 blocks x 256 thr = 1024 fully-independent waves (1/SIMD), NO in-loop
// barriers. Each wave: 4 batches, all 4 gates x 64 hidden (16 D-tiles); rows =
// 4*batch + q (4-step time-pack, full M=16). R10 vs R9 (which spilled at 256
// VGPR + 11MB scratch writes): (1) wih B-frags are wave-invariant -> ONE shared
// 32KB LDS copy, read once per pack; (2) bias enters via the dead k=40 input
// channel (x k=40 ch == 1.0) -> zacc zero-init; (3) w_clf loaded inline (only
// acl depends on it -> off the recurrence chain). Live regs ~240: no spill.
__global__ __launch_bounds__(256, 1)
void lstm_w2(const float* __restrict__ x, const float* __restrict__ w_ih,
             const float* __restrict__ w_hh, const float* __restrict__ b_ih,
             const float* __restrict__ b_hh, const float* __restrict__ w_clf,
             const float* __restrict__ b_clf, float* __restrict__ out) {
  __shared__ f16x8 wih_lds[4][4][2][64];   // 32 KB, [gate][j][kc][lane], shared by all waves
  __shared__ ushort_t hscr[4][4][80];      // 2.5 KB, wave-private h scratch

  const int tid = threadIdx.x;
  const int l   = tid & 63;
  const int wv  = tid >> 6;
  const int c15 = l & 15;
  const int g16 = l >> 4;
  const int b0  = blockIdx.x * 16 + wv * 4;

  const float gsc[4] = {LOG2E, LOG2E, 2.0f * LOG2E, LOG2E};

  // ---- stage wih (wave wv handles gate g=wv), bias into k=40 channel ----
  {
    const int g = wv;
    const float s = gsc[g];
#pragma unroll
    for (int j = 0; j < 4; ++j) {
      const int n = 16 * j + c15;
      const float* wi = w_ih + (size_t)(g * 64 + n) * IN_DIM;
      float4 v0 = *(const float4*)(wi + g16 * 8);      // k = 8*g16..+7 <= 31
      float4 v1 = *(const float4*)(wi + g16 * 8 + 4);
      v0.x *= s; v0.y *= s; v0.z *= s; v0.w *= s;
      v1.x *= s; v1.y *= s; v1.z *= s; v1.w *= s;
      wih_lds[g][j][0][l] = cvt8h(v0, v1);
      float4 u0 = make_float4(0, 0, 0, 0), u1 = make_float4(0, 0, 0, 0);
      if (g16 == 0) {                                  // k = 32..39
        u0 = *(const float4*)(wi + 32);
        u1 = *(const float4*)(wi + 36);
        u0.x *= s; u0.y *= s; u0.z *= s; u0.w *= s;
        u1.x *= s; u1.y *= s; u1.z *= s; u1.w *= s;
      } else if (g16 == 1) {                           // k = 40: bias channel
        u0.x = (b_ih[g * 64 + n] + b_hh[g * 64 + n]) * s;
      }
      wih_lds[g][j][1][l] = cvt8h(u0, u1);
    }
  }

  // ---- whh in registers (fp16, prescaled): 128 VGPRs ----
  f16x8 whh[4][4][2];
#pragma unroll
  for (int g = 0; g < 4; ++g) {
    const float s = gsc[g];
#pragma unroll
    for (int j = 0; j < 4; ++j) {
      const int n = 16 * j + c15;
      const float* wr = w_hh + (size_t)(g * 64 + n) * 64;
#pragma unroll
      for (int kc = 0; kc < 2; ++kc) {
        float4 v0 = *(const float4*)(wr + kc * 32 + g16 * 8);
        float4 v1 = *(const float4*)(wr + kc * 32 + g16 * 8 + 4);
        v0.x *= s; v0.y *= s; v0.z *= s; v0.w *= s;
        v1.x *= s; v1.y *= s; v1.z *= s; v1.w *= s;
        whh[g][j][kc] = cvt8h(v0, v1);
      }
    }
  }

  // zero this wave's h scratch (h[-1] = 0)
  for (int i = l; i < 320; i += 64) (&hscr[wv][0][0])[i] = 0;
  __syncthreads();   // wih_lds visible to all waves (once; not in the loop)

  const int s_a = c15 >> 2, q_a = c15 & 3;
  const float* xb = x + (size_t)(b0 + s_a) * T_STEPS * IN_DIM;

  // x prefetch for pack 0 (lane time = q_a); kc=1: g16==0 real k=32..39,
  // g16==1 = bias channel constant (1,0,...,0), g16>=2 zero.
  float4 xa0 = *(const float4*)(xb + q_a * IN_DIM + g16 * 8);
  float4 xa1 = *(const float4*)(xb + q_a * IN_DIM + g16 * 8 + 4);
  float4 xq0 = make_float4(0, 0, 0, 0), xq1 = make_float4(0, 0, 0, 0);
  if (g16 == 0) {
    xq0 = *(const float4*)(xb + q_a * IN_DIM + 32);
    xq1 = *(const float4*)(xb + q_a * IN_DIM + 36);
  } else if (g16 == 1) {
    xq0.x = 1.0f;                    // k = 40 -> bias row multiplier
  }

  f32x4 z[4][4];
  float cc[4]  = {0.f, 0.f, 0.f, 0.f};
  float acl[4] = {0.f, 0.f, 0.f, 0.f};

  const f16x8* const rd0 = (const f16x8*)&hscr[wv][s_a][8 * g16];
  const f16x8* const rd1 = (const f16x8*)&hscr[wv][s_a][32 + 8 * g16];
  ushort_t* const wb = &hscr[wv][g16][0];

  asm volatile("s_waitcnt lgkmcnt(0)" ::: "memory");   // scratch zeros visible

#define RSTEP(Q, TCUR)                                                            \
  {                                                                               \
    f16x8 a0 = *rd0, a1 = *rd1;                                                   \
    const f16x8 fz = {};                                                          \
    if (q_a != (Q)) { a0 = fz; a1 = fz; }                                         \
    _Pragma("unroll")                                                             \
    for (int g = 0; g < 4; ++g) {                                                 \
      _Pragma("unroll")                                                           \
      for (int j = 0; j < 4; ++j) {                                               \
        z[g][j] = __builtin_amdgcn_mfma_f32_16x16x32_f16(a0, whh[g][j][0], z[g][j], 0, 0, 0); \
        z[g][j] = __builtin_amdgcn_mfma_f32_16x16x32_f16(a1, whh[g][j][1], z[g][j], 0, 0, 0); \
      }                                                                           \
    }                                                                             \
    const float* wcp = w_clf + (TCUR) * 64 + c15;                                 \
    _Pragma("unroll")                                                             \
    for (int j = 0; j < 4; ++j) {                                                 \
      const float h = lstm_act(z[0][j][Q], z[1][j][Q], z[2][j][Q], z[3][j][Q], cc[j]); \
      acl[j] += h * wcp[16 * j];                                                  \
      union { _Float16 hf; ushort_t u; } cv; cv.hf = (_Float16)h;                 \
      wb[16 * j + c15] = cv.u;                                                    \
    }                                                                             \
    asm volatile("s_waitcnt lgkmcnt(0)" ::: "memory");                            \
  }

  for (int p = 0; p <= 75; ++p) {
    const int t0 = 4 * p;
    // ---- xproj volley: z = x[t0..t0+3] @ wih^T (+bias via k=40), full M=16 ----
    {
      const f16x8 xf0 = cvt8h(xa0, xa1);
      const f16x8 xf1 = cvt8h(xq0, xq1);
#pragma unroll
      for (int g = 0; g < 4; ++g) {
#pragma unroll
        for (int j = 0; j < 4; ++j) {
          f32x4 zz = {0.f, 0.f, 0.f, 0.f};
          zz = __builtin_amdgcn_mfma_f32_16x16x32_f16(xf0, wih_lds[g][j][0][l], zz, 0, 0, 0);
          z[g][j] = __builtin_amdgcn_mfma_f32_16x16x32_f16(xf1, wih_lds[g][j][1][l], zz, 0, 0, 0);
        }
      }
      if (t0 + 4 < T_STEPS) {        // prefetch x for next pack
        const int tq = t0 + 4 + q_a;
        const int tm = (tq <= T_STEPS - 1) ? tq : T_STEPS - 1;
        const float* xp = xb + (size_t)tm * IN_DIM + g16 * 8;
        xa0 = *(const float4*)xp;
        xa1 = *(const float4*)(xp + 4);
        if (g16 == 0) {
          xq0 = *(const float4*)(xb + (size_t)tm * IN_DIM + 32);
          xq1 = *(const float4*)(xb + (size_t)tm * IN_DIM + 36);
        }
      }
    }
    RSTEP(0, t0)
    if (t0 + 1 >= T_STEPS) break;    // t0 == 300 (uniform across grid)
    RSTEP(1, t0 + 1)
    RSTEP(2, t0 + 2)
    RSTEP(3, t0 + 3)
  }
#undef RSTEP

  // ---- epilogue: in-wave reduce over the 16 c15-lanes per batch ----
  float a = acl[0] + acl[1] + acl[2] + acl[3];
  a += __shfl_xor(a, 1);
  a += __shfl_xor(a, 2);
  a += __shfl_xor(a, 4);
  a += __shfl_xor(a, 8);
  if (c15 == 0) out[b0 + g16] = a + b_clf[0];
}

extern "C" void kernel_launch(void* const* d_in, const int* in_sizes, int n_in,
                              void* d_out, int out_size, void* d_ws, size_t ws_size,
                              hipStream_t stream) {
  const float* x     = (const float*)d_in[0];
  const float* w_ih  = (const float*)d_in[1];
  const float* w_hh  = (const float*)d_in[2];
  const float* b_ih  = (const float*)d_in[3];
  const float* b_hh  = (const float*)d_in[4];
  const float* w_clf = (const float*)d_in[5];
  const float* b_clf = (const float*)d_in[6];
  float* out = (float*)d_out;

  lstm_w2<<<256, 256, 0, stream>>>(x, w_ih, w_hh, b_ih, b_hh, w_clf, b_clf, out);
}

// Round 11
// 230.844 us; speedup vs baseline: 1.0509x; 1.0509x over previous
//
#include <hip/hip_runtime.h>

#define T_STEPS 301
#define IN_DIM  40
#define LOG2E   1.44269504088896340736f

typedef __attribute__((ext_vector_type(8))) _Float16 f16x8;
typedef __attribute__((ext_vector_type(4))) float f32x4;
typedef unsigned short ushort_t;
typedef unsigned int uint_t;

union u16cv { _Float16 hf; ushort_t u; };

#define MFMA16(A, B, C) __builtin_amdgcn_mfma_f32_16x16x32_f16((A), (B), (C), 0, 0, 0)

__device__ __forceinline__ f16x8 cvt8h(const float4 a, const float4 b) {
  f16x8 r;
  r[0] = (_Float16)a.x; r[1] = (_Float16)a.y; r[2] = (_Float16)a.z; r[3] = (_Float16)a.w;
  r[4] = (_Float16)b.x; r[5] = (_Float16)b.y; r[6] = (_Float16)b.z; r[7] = (_Float16)b.w;
  return r;
}

// z pre-scaled by log2e (2*log2e for g-gate) -> exp2-based activations.
__device__ __forceinline__ float lstm_act(float zi, float zf, float zg, float zo, float& cc) {
  const float ig = __builtin_amdgcn_rcpf(1.0f + __builtin_amdgcn_exp2f(-zi));
  const float fg = __builtin_amdgcn_rcpf(1.0f + __builtin_amdgcn_exp2f(-zf));
  const float gg = 1.0f - 2.0f * __builtin_amdgcn_rcpf(1.0f + __builtin_amdgcn_exp2f(zg));
  const float og = __builtin_amdgcn_rcpf(1.0f + __builtin_amdgcn_exp2f(-zo));
  cc = fg * cc + ig * gg;
  const float tc = 1.0f - 2.0f * __builtin_amdgcn_rcpf(1.0f + __builtin_amdgcn_exp2f(cc * (2.0f * LOG2E)));
  return og * tc;
}

// 256 blocks x 256 thr = 1024 independent waves (1/SIMD), NO in-loop barriers.
// Per wave: 4 batches x 64 hidden x 4 gates (16 D-tiles), rows = 4*batch + q
// (4-step time-pack, full M=16). R11 chain-shortening vs R10:
//  (1) h slots [4] rotating in LDS; per-lane read ptr = live slot iff q_a==Q
//      else a never-written zero buffer -> zero per-step masking VALU.
//  (2) w_clf staged to LDS once -> per-step broadcast ds_read, no global/vmcnt.
//  (3) j-split pipeline: MFMA j01 -> act j01/write -> MFMA j23(kc1) ->
//      read next kc0 -> act j23/write -> read next kc1 (overlaps act with MFMA
//      and splits the write->read round trip).
//  (4) no explicit lgkm drains (compiler-managed), x held pre-converted f16.
__global__ __launch_bounds__(256, 1)
void lstm_w3(const float* __restrict__ x, const float* __restrict__ w_ih,
             const float* __restrict__ w_hh, const float* __restrict__ b_ih,
             const float* __restrict__ b_hh, const float* __restrict__ w_clf,
             const float* __restrict__ b_clf, float* __restrict__ out) {
  extern __shared__ char smem[];
  f16x8*    wih_lds = (f16x8*)smem;                            // [g][j][kc][64], 32 KB
  float*    wclf    = (float*)(smem + 32768);                  // [301][64], 77056 B
  ushort_t* hscr    = (ushort_t*)(smem + 32768 + 77056);       // [wv][slot4][s4][80]
  ushort_t* zb      = (ushort_t*)(smem + 32768 + 77056 + 10240); // [80] zeros

  const int tid = threadIdx.x;
  const int l   = tid & 63, wv = tid >> 6;
  const int c15 = l & 15, g16 = l >> 4;
  const int b0  = blockIdx.x * 16 + wv * 4;
  const float gsc[4] = {LOG2E, LOG2E, 2.0f * LOG2E, LOG2E};

  // ---- stage wih (wave wv -> gate wv), bias in k=40 channel ----
  {
    const int g = wv;
    const float s = gsc[g];
#pragma unroll
    for (int j = 0; j < 4; ++j) {
      const int n = 16 * j + c15;
      const float* wi = w_ih + (size_t)(g * 64 + n) * IN_DIM;
      float4 v0 = *(const float4*)(wi + g16 * 8);
      float4 v1 = *(const float4*)(wi + g16 * 8 + 4);
      v0.x *= s; v0.y *= s; v0.z *= s; v0.w *= s;
      v1.x *= s; v1.y *= s; v1.z *= s; v1.w *= s;
      wih_lds[((g * 4 + j) * 2 + 0) * 64 + l] = cvt8h(v0, v1);
      float4 u0 = make_float4(0, 0, 0, 0), u1 = make_float4(0, 0, 0, 0);
      if (g16 == 0) {
        u0 = *(const float4*)(wi + 32);
        u1 = *(const float4*)(wi + 36);
        u0.x *= s; u0.y *= s; u0.z *= s; u0.w *= s;
        u1.x *= s; u1.y *= s; u1.z *= s; u1.w *= s;
      } else if (g16 == 1) {
        u0.x = (b_ih[g * 64 + n] + b_hh[g * 64 + n]) * s;   // k=40 bias row
      }
      wih_lds[((g * 4 + j) * 2 + 1) * 64 + l] = cvt8h(u0, u1);
    }
  }
  for (int i = tid; i < T_STEPS * 64; i += 256) wclf[i] = w_clf[i];
  for (int i = tid; i < 5200; i += 256) hscr[i] = 0;   // hscr (5120) + zb (80)

  // ---- whh in registers (fp16, prescaled) ----
  f16x8 whh[4][4][2];
#pragma unroll
  for (int g = 0; g < 4; ++g) {
    const float s = gsc[g];
#pragma unroll
    for (int j = 0; j < 4; ++j) {
      const int n = 16 * j + c15;
      const float* wr = w_hh + (size_t)(g * 64 + n) * 64;
#pragma unroll
      for (int kc = 0; kc < 2; ++kc) {
        float4 v0 = *(const float4*)(wr + kc * 32 + g16 * 8);
        float4 v1 = *(const float4*)(wr + kc * 32 + g16 * 8 + 4);
        v0.x *= s; v0.y *= s; v0.z *= s; v0.w *= s;
        v1.x *= s; v1.y *= s; v1.z *= s; v1.w *= s;
        whh[g][j][kc] = cvt8h(v0, v1);
      }
    }
  }
  __syncthreads();   // staging visible (once; never again)

  const int s_a = c15 >> 2, q_a = c15 & 3;
  // loop-invariant read ptrs: live slot iff q_a == Q, else zero buffer
  const ushort_t* const rdp0 = (q_a == 0) ? &hscr[(wv * 16 + 0 * 4 + s_a) * 80 + 8 * g16] : &zb[8 * g16];
  const ushort_t* const rdp1 = (q_a == 1) ? &hscr[(wv * 16 + 1 * 4 + s_a) * 80 + 8 * g16] : &zb[8 * g16];
  const ushort_t* const rdp2 = (q_a == 2) ? &hscr[(wv * 16 + 2 * 4 + s_a) * 80 + 8 * g16] : &zb[8 * g16];
  const ushort_t* const rdp3 = (q_a == 3) ? &hscr[(wv * 16 + 3 * 4 + s_a) * 80 + 8 * g16] : &zb[8 * g16];
  ushort_t* const wbase = &hscr[wv * 1280 + g16 * 80 + c15];   // + slot*320 + 16*j

  // x prefetch, pre-converted to f16 frags (pack 0: lane time = q_a)
  const float* xb = x + (size_t)(b0 + s_a) * T_STEPS * IN_DIM;
  f16x8 xfa, xfb;
  {
    const float4 v0 = *(const float4*)(xb + q_a * IN_DIM + g16 * 8);
    const float4 v1 = *(const float4*)(xb + q_a * IN_DIM + g16 * 8 + 4);
    xfa = cvt8h(v0, v1);
    float4 u0 = make_float4(0, 0, 0, 0), u1 = make_float4(0, 0, 0, 0);
    if (g16 == 0) {
      u0 = *(const float4*)(xb + q_a * IN_DIM + 32);
      u1 = *(const float4*)(xb + q_a * IN_DIM + 36);
    } else if (g16 == 1) {
      u0.x = 1.0f;                 // k=40 bias channel
    }
    xfb = cvt8h(u0, u1);
  }

  f32x4 z[4][4];
  float cc[4]  = {0.f, 0.f, 0.f, 0.f};
  float acl[4] = {0.f, 0.f, 0.f, 0.f};
  const float* wcp = wclf + c15;

  f16x8 a0 = *(const f16x8*)rdp0;          // step 0 frags (slot 0 = zeros)
  f16x8 a1 = *(const f16x8*)(rdp0 + 32);

#define RSTEP(Q, NS, RDN)                                                         \
  {                                                                               \
    _Pragma("unroll")                                                             \
    for (int g = 0; g < 4; ++g) {                                                 \
      z[g][0] = MFMA16(a0, whh[g][0][0], z[g][0]);                                \
      z[g][0] = MFMA16(a1, whh[g][0][1], z[g][0]);                                \
      z[g][1] = MFMA16(a0, whh[g][1][0], z[g][1]);                                \
      z[g][1] = MFMA16(a1, whh[g][1][1], z[g][1]);                                \
    }                                                                             \
    _Pragma("unroll")                                                             \
    for (int g = 0; g < 4; ++g) {                                                 \
      z[g][2] = MFMA16(a0, whh[g][2][0], z[g][2]);                                \
      z[g][3] = MFMA16(a0, whh[g][3][0], z[g][3]);                                \
    }                                                                             \
    const float wcA = wcp[0], wcB = wcp[16];                                      \
    {                                                                             \
      const float h = lstm_act(z[0][0][Q], z[1][0][Q], z[2][0][Q], z[3][0][Q], cc[0]); \
      acl[0] += h * wcA;                                                          \
      u16cv cv; cv.hf = (_Float16)h; wbase[(NS) * 320 + 0] = cv.u;                \
    }                                                                             \
    {                                                                             \
      const float h = lstm_act(z[0][1][Q], z[1][1][Q], z[2][1][Q], z[3][1][Q], cc[1]); \
      acl[1] += h * wcB;                                                          \
      u16cv cv; cv.hf = (_Float16)h; wbase[(NS) * 320 + 16] = cv.u;               \
    }                                                                             \
    _Pragma("unroll")                                                             \
    for (int g = 0; g < 4; ++g) {                                                 \
      z[g][2] = MFMA16(a1, whh[g][2][1], z[g][2]);                                \
      z[g][3] = MFMA16(a1, whh[g][3][1], z[g][3]);                                \
    }                                                                             \
    a0 = *(const f16x8*)(RDN);                    /* next kc0: needs j01 only */  \
    const float wcC = wcp[32], wcD = wcp[48];                                     \
    {                                                                             \
      const float h = lstm_act(z[0][2][Q], z[1][2][Q], z[2][2][Q], z[3][2][Q], cc[2]); \
      acl[2] += h * wcC;                                                          \
      u16cv cv; cv.hf = (_Float16)h; wbase[(NS) * 320 + 32] = cv.u;               \
    }                                                                             \
    {                                                                             \
      const float h = lstm_act(z[0][3][Q], z[1][3][Q], z[2][3][Q], z[3][3][Q], cc[3]); \
      acl[3] += h * wcD;                                                          \
      u16cv cv; cv.hf = (_Float16)h; wbase[(NS) * 320 + 48] = cv.u;               \
    }                                                                             \
    a1 = *(const f16x8*)((RDN) + 32);             /* next kc1: after j23 writes */\
    wcp += 64;                                                                    \
  }

  for (int p = 0; p <= 75; ++p) {
    const int t0 = 4 * p;
    // ---- xproj volley: z = x[t0..t0+3] @ wih^T (+bias via k=40), full M=16 ----
#pragma unroll
    for (int g = 0; g < 4; ++g) {
#pragma unroll
      for (int j = 0; j < 4; ++j) {
        f32x4 zz = {0.f, 0.f, 0.f, 0.f};
        zz = MFMA16(xfa, wih_lds[((g * 4 + j) * 2 + 0) * 64 + l], zz);
        z[g][j] = MFMA16(xfb, wih_lds[((g * 4 + j) * 2 + 1) * 64 + l], zz);
      }
    }
    if (t0 + 4 < T_STEPS) {   // prefetch next pack's x (in flight across steps)
      const int tq = t0 + 4 + q_a;
      const int tm = (tq <= T_STEPS - 1) ? tq : T_STEPS - 1;
      const float4 v0 = *(const float4*)(xb + (size_t)tm * IN_DIM + g16 * 8);
      const float4 v1 = *(const float4*)(xb + (size_t)tm * IN_DIM + g16 * 8 + 4);
      xfa = cvt8h(v0, v1);
      float4 u0 = make_float4(0, 0, 0, 0), u1 = make_float4(0, 0, 0, 0);
      if (g16 == 0) {
        u0 = *(const float4*)(xb + (size_t)tm * IN_DIM + 32);
        u1 = *(const float4*)(xb + (size_t)tm * IN_DIM + 36);
      } else if (g16 == 1) {
        u0.x = 1.0f;
      }
      xfb = cvt8h(u0, u1);
    }
    RSTEP(0, 1, rdp1)
    if (t0 + 1 >= T_STEPS) break;      // t0 == 300 (uniform across grid)
    RSTEP(1, 2, rdp2)
    RSTEP(2, 3, rdp3)
    RSTEP(3, 0, rdp0)
  }
#undef RSTEP

  // ---- epilogue: in-wave reduce over the 16 c15-lanes per batch ----
  float a = acl[0] + acl[1] + acl[2] + acl[3];
  a += __shfl_xor(a, 1);
  a += __shfl_xor(a, 2);
  a += __shfl_xor(a, 4);
  a += __shfl_xor(a, 8);
  if (c15 == 0) out[b0 + g16] = a + b_clf[0];
}

extern "C" void kernel_launch(void* const* d_in, const int* in_sizes, int n_in,
                              void* d_out, int out_size, void* d_ws, size_t ws_size,
                              hipStream_t stream) {
  const float* x     = (const float*)d_in[0];
  const float* w_ih  = (const float*)d_in[1];
  const float* w_hh  = (const float*)d_in[2];
  const float* b_ih  = (const float*)d_in[3];
  const float* b_hh  = (const float*)d_in[4];
  const float* w_clf = (const float*)d_in[5];
  const float* b_clf = (const float*)d_in[6];
  float* out = (float*)d_out;

  const size_t shmem = 32768 + 77056 + 10240 + 160;   // ~117.4 KB dynamic LDS
  (void)hipFuncSetAttribute((const void*)lstm_w3,
                            hipFuncAttributeMaxDynamicSharedMemorySize, (int)shmem);
  lstm_w3<<<256, 256, shmem, stream>>>(x, w_ih, w_hh, b_ih, b_hh, w_clf, b_clf, out);
}

// Round 12
// 216.572 us; speedup vs baseline: 1.1202x; 1.0659x over previous
//
#include <hip/hip_runtime.h>

#define T_STEPS 301
#define IN_DIM  40
#define LOG2E   1.44269504088896340736f

typedef __attribute__((ext_vector_type(8))) _Float16 f16x8;
typedef __attribute__((ext_vector_type(4))) float f32x4;
typedef unsigned short ushort_t;

union u16cv { _Float16 hf; ushort_t u; };

#define MFMA16(A, B, C) __builtin_amdgcn_mfma_f32_16x16x32_f16((A), (B), (C), 0, 0, 0)

__device__ __forceinline__ f16x8 cvt8h(const float4 a, const float4 b) {
  f16x8 r;
  r[0] = (_Float16)a.x; r[1] = (_Float16)a.y; r[2] = (_Float16)a.z; r[3] = (_Float16)a.w;
  r[4] = (_Float16)b.x; r[5] = (_Float16)b.y; r[6] = (_Float16)b.z; r[7] = (_Float16)b.w;
  return r;
}

// z pre-scaled by log2e (2*log2e for g-gate) -> exp2-based activations.
__device__ __forceinline__ float lstm_act(float zi, float zf, float zg, float zo, float& cc) {
  const float ig = __builtin_amdgcn_rcpf(1.0f + __builtin_amdgcn_exp2f(-zi));
  const float fg = __builtin_amdgcn_rcpf(1.0f + __builtin_amdgcn_exp2f(-zf));
  const float gg = 1.0f - 2.0f * __builtin_amdgcn_rcpf(1.0f + __builtin_amdgcn_exp2f(zg));
  const float og = __builtin_amdgcn_rcpf(1.0f + __builtin_amdgcn_exp2f(-zo));
  cc = fg * cc + ig * gg;
  const float tc = 1.0f - 2.0f * __builtin_amdgcn_rcpf(1.0f + __builtin_amdgcn_exp2f(cc * (2.0f * LOG2E)));
  return og * tc;
}

// 1024 blocks x 128 thr (2 waves) -> 4 blocks/CU, 2 waves/SIMD (VGPR<=128).
// Block = 4 batches; wave wv owns hidden half [32wv, 32wv+32) for all 4 gates:
// zacc = 8 tiles (32 reg), whh = 8 frags (64 reg). 4-step time-pack: A/D rows =
// 4*batch + q; xproj volley (wih from LDS) once per 4 steps; each step's
// recurrent MFMA updates reg q only (A rows for q'!=q read a zero buffer via
// precomputed pointer select). h exchange: 4-slot rotating LDS buffer (stride
// padded 64->72 to break 128B bank periodicity); per-step sync = s_barrier of
// a 2-wave block only. One cell state pair per thread (batch g16, n = 32wv+16j+c15).
__global__ __launch_bounds__(128, 2)
void lstm_p2(const float* __restrict__ x, const float* __restrict__ w_ih,
             const float* __restrict__ w_hh, const float* __restrict__ b_ih,
             const float* __restrict__ b_hh, const float* __restrict__ w_clf,
             const float* __restrict__ b_clf, float* __restrict__ out) {
  __shared__ f16x8 wih_lds[2][4][2][2][64];   // 32 KB [half][gate][j][kc][lane]
  __shared__ ushort_t hb[4][4][72];           // 4.5 KB [slot][batch][64 n + 8 pad]
  __shared__ ushort_t zbuf[48];               // never-written zero A-frag source
  __shared__ float red[2][4];

  const int tid = threadIdx.x;
  const int l   = tid & 63, wv = tid >> 6;    // wv = hidden half
  const int c15 = l & 15, g16 = l >> 4;
  const int b0  = blockIdx.x * 4;
  const float gsc[4] = {LOG2E, LOG2E, 2.0f * LOG2E, LOG2E};

  // ---- stage wih (+bias k=40 channel) into LDS: 2048 frags / 128 thr ----
  for (int idx = tid; idx < 2048; idx += 128) {
    const int l2 = idx & 63;
    const int kc = (idx >> 6) & 1;
    const int j  = (idx >> 7) & 1;
    const int g  = (idx >> 8) & 3;
    const int hv = idx >> 10;
    const int n  = hv * 32 + j * 16 + (l2 & 15);
    const int kg = l2 >> 4;
    const float s = gsc[g];
    const float* wi = w_ih + (size_t)(g * 64 + n) * IN_DIM;
    float4 v0 = make_float4(0, 0, 0, 0), v1 = make_float4(0, 0, 0, 0);
    if (kc == 0) {                       // k = 8*kg .. +7  (< 32 < 40)
      v0 = *(const float4*)(wi + kg * 8);
      v1 = *(const float4*)(wi + kg * 8 + 4);
      v0.x *= s; v0.y *= s; v0.z *= s; v0.w *= s;
      v1.x *= s; v1.y *= s; v1.z *= s; v1.w *= s;
    } else if (kg == 0) {                // k = 32..39
      v0 = *(const float4*)(wi + 32);
      v1 = *(const float4*)(wi + 36);
      v0.x *= s; v0.y *= s; v0.z *= s; v0.w *= s;
      v1.x *= s; v1.y *= s; v1.z *= s; v1.w *= s;
    } else if (kg == 1) {                // k = 40: bias channel
      v0.x = (b_ih[g * 64 + n] + b_hh[g * 64 + n]) * s;
    }
    wih_lds[hv][g][j][kc][l2] = cvt8h(v0, v1);
  }

  // ---- whh B-frags in registers (this wave's n-half): 64 VGPR ----
  f16x8 whh[4][2][2];
#pragma unroll
  for (int g = 0; g < 4; ++g) {
    const float s = gsc[g];
#pragma unroll
    for (int j = 0; j < 2; ++j) {
      const int n = wv * 32 + 16 * j + c15;
      const float* wr = w_hh + (size_t)(g * 64 + n) * 64;
#pragma unroll
      for (int kc = 0; kc < 2; ++kc) {
        float4 v0 = *(const float4*)(wr + kc * 32 + g16 * 8);
        float4 v1 = *(const float4*)(wr + kc * 32 + g16 * 8 + 4);
        v0.x *= s; v0.y *= s; v0.z *= s; v0.w *= s;
        v1.x *= s; v1.y *= s; v1.z *= s; v1.w *= s;
        whh[g][j][kc] = cvt8h(v0, v1);
      }
    }
  }

  // zero h slots + zero buffer
  {
    ushort_t* p = &hb[0][0][0];
    for (int i = tid; i < 1152; i += 128) p[i] = 0;
    if (tid < 48) zbuf[tid] = 0;
  }
  __syncthreads();

  // A-side lane mapping: row r15 = 4*s_a + q_a
  const int s_a = (l & 15) >> 2, q_a = l & 3;
  const ushort_t* const rdp0 = (q_a == 0) ? &hb[0][s_a][8 * g16] : &zbuf[0];
  const ushort_t* const rdp1 = (q_a == 1) ? &hb[1][s_a][8 * g16] : &zbuf[0];
  const ushort_t* const rdp2 = (q_a == 2) ? &hb[2][s_a][8 * g16] : &zbuf[0];
  const ushort_t* const rdp3 = (q_a == 3) ? &hb[3][s_a][8 * g16] : &zbuf[0];
  ushort_t* const wr0 = &hb[0][g16][wv * 32 + c15];   // + slot*288 + j*16

  // x prefetch (pack 0, lane time = q_a), pre-converted fp16
  const float* xb = x + (size_t)(b0 + s_a) * T_STEPS * IN_DIM;
  f16x8 xfa, xfb;
  {
    const float4 v0 = *(const float4*)(xb + q_a * IN_DIM + g16 * 8);
    const float4 v1 = *(const float4*)(xb + q_a * IN_DIM + g16 * 8 + 4);
    xfa = cvt8h(v0, v1);
    float4 u0 = make_float4(0, 0, 0, 0), u1 = make_float4(0, 0, 0, 0);
    if (g16 == 0) {
      u0 = *(const float4*)(xb + q_a * IN_DIM + 32);
      u1 = *(const float4*)(xb + q_a * IN_DIM + 36);
    } else if (g16 == 1) {
      u0.x = 1.0f;                      // k=40 bias multiplier
    }
    xfb = cvt8h(u0, u1);
  }

  f32x4 z[4][2];
  float cc[2]  = {0.f, 0.f};
  float acl[2] = {0.f, 0.f};

#define RSTEP(Q, RDP)                                                             \
  {                                                                               \
    f16x8 a0 = *(const f16x8*)(RDP);                                              \
    f16x8 a1 = *(const f16x8*)((RDP) + 32);                                       \
    _Pragma("unroll")                                                             \
    for (int g = 0; g < 4; ++g) {                                                 \
      z[g][0] = MFMA16(a0, whh[g][0][0], z[g][0]);                                \
      z[g][0] = MFMA16(a1, whh[g][0][1], z[g][0]);                                \
      z[g][1] = MFMA16(a0, whh[g][1][0], z[g][1]);                                \
      z[g][1] = MFMA16(a1, whh[g][1][1], z[g][1]);                                \
    }                                                                             \
    const float* wcp = w_clf + (t0 + (Q)) * 64 + wv * 32 + c15;                   \
    const float wcA = wcp[0], wcB = wcp[16];                                      \
    const float h0 = lstm_act(z[0][0][Q], z[1][0][Q], z[2][0][Q], z[3][0][Q], cc[0]); \
    acl[0] += h0 * wcA;                                                           \
    const float h1 = lstm_act(z[0][1][Q], z[1][1][Q], z[2][1][Q], z[3][1][Q], cc[1]); \
    acl[1] += h1 * wcB;                                                           \
    u16cv c0, c1; c0.hf = (_Float16)h0; c1.hf = (_Float16)h1;                     \
    ushort_t* wp = wr0 + ((((Q) + 1) & 3) * 288);                                 \
    wp[0]  = c0.u;                                                                \
    wp[16] = c1.u;                                                                \
    asm volatile("s_waitcnt lgkmcnt(0)\n\ts_barrier" ::: "memory");               \
  }

  for (int p = 0; p <= 75; ++p) {
    const int t0 = 4 * p;
    // ---- xproj volley: z = x[t0..t0+3] @ wih^T (+bias via k=40), full M=16 ----
#pragma unroll
    for (int g = 0; g < 4; ++g) {
#pragma unroll
      for (int j = 0; j < 2; ++j) {
        f32x4 zz = {0.f, 0.f, 0.f, 0.f};
        zz = MFMA16(xfa, wih_lds[wv][g][j][0][l], zz);
        z[g][j] = MFMA16(xfb, wih_lds[wv][g][j][1][l], zz);
      }
    }
    if (t0 + 4 < T_STEPS) {              // prefetch next pack's x
      const int tq = t0 + 4 + q_a;
      const int tm = (tq <= T_STEPS - 1) ? tq : T_STEPS - 1;
      const float4 v0 = *(const float4*)(xb + (size_t)tm * IN_DIM + g16 * 8);
      const float4 v1 = *(const float4*)(xb + (size_t)tm * IN_DIM + g16 * 8 + 4);
      xfa = cvt8h(v0, v1);
      float4 u0 = make_float4(0, 0, 0, 0), u1 = make_float4(0, 0, 0, 0);
      if (g16 == 0) {
        u0 = *(const float4*)(xb + (size_t)tm * IN_DIM + 32);
        u1 = *(const float4*)(xb + (size_t)tm * IN_DIM + 36);
      } else if (g16 == 1) {
        u0.x = 1.0f;
      }
      xfb = cvt8h(u0, u1);
    }
    RSTEP(0, rdp0)
    if (t0 + 1 >= T_STEPS) break;        // t0 == 300 (uniform across grid)
    RSTEP(1, rdp1)
    RSTEP(2, rdp2)
    RSTEP(3, rdp3)
  }
#undef RSTEP

  // ---- epilogue: reduce over c15 lanes, then across the 2 waves ----
  float aa = acl[0] + acl[1];
  aa += __shfl_xor(aa, 1);
  aa += __shfl_xor(aa, 2);
  aa += __shfl_xor(aa, 4);
  aa += __shfl_xor(aa, 8);
  if (c15 == 0) red[wv][g16] = aa;
  __syncthreads();
  if (tid < 4) out[b0 + tid] = red[0][tid] + red[1][tid] + b_clf[0];
}

extern "C" void kernel_launch(void* const* d_in, const int* in_sizes, int n_in,
                              void* d_out, int out_size, void* d_ws, size_t ws_size,
                              hipStream_t stream) {
  const float* x     = (const float*)d_in[0];
  const float* w_ih  = (const float*)d_in[1];
  const float* w_hh  = (const float*)d_in[2];
  const float* b_ih  = (const float*)d_in[3];
  const float* b_hh  = (const float*)d_in[4];
  const float* w_clf = (const float*)d_in[5];
  const float* b_clf = (const float*)d_in[6];
  float* out = (float*)d_out;

  lstm_p2<<<1024, 128, 0, stream>>>(x, w_ih, w_hh, b_ih, b_hh, w_clf, b_clf, out);
}

// Round 13
// 181.476 us; speedup vs baseline: 1.3368x; 1.1934x over previous
//
#include <hip/hip_runtime.h>

#define T_STEPS 301
#define IN_DIM  40
#define LOG2E   1.44269504088896340736f

typedef __attribute__((ext_vector_type(8))) _Float16 f16x8;
typedef __attribute__((ext_vector_type(4))) float f32x4;
typedef unsigned short ushort_t;
typedef unsigned int uint_t;

union u16cv { _Float16 hf; ushort_t u; };

#define MFMA16(A, B, C) __builtin_amdgcn_mfma_f32_16x16x32_f16((A), (B), (C), 0, 0, 0)

__device__ __forceinline__ f16x8 cvt8h(const float4 a, const float4 b) {
  f16x8 r;
  r[0] = (_Float16)a.x; r[1] = (_Float16)a.y; r[2] = (_Float16)a.z; r[3] = (_Float16)a.w;
  r[4] = (_Float16)b.x; r[5] = (_Float16)b.y; r[6] = (_Float16)b.z; r[7] = (_Float16)b.w;
  return r;
}

// z pre-scaled by log2e (2*log2e for g-gate) -> exp2-based activations.
__device__ __forceinline__ float lstm_act(float zi, float zf, float zg, float zo, float& cc) {
  const float ig = __builtin_amdgcn_rcpf(1.0f + __builtin_amdgcn_exp2f(-zi));
  const float fg = __builtin_amdgcn_rcpf(1.0f + __builtin_amdgcn_exp2f(-zf));
  const float gg = 1.0f - 2.0f * __builtin_amdgcn_rcpf(1.0f + __builtin_amdgcn_exp2f(zg));
  const float og = __builtin_amdgcn_rcpf(1.0f + __builtin_amdgcn_exp2f(-zo));
  cc = fg * cc + ig * gg;
  const float tc = 1.0f - 2.0f * __builtin_amdgcn_rcpf(1.0f + __builtin_amdgcn_exp2f(cc * (2.0f * LOG2E)));
  return og * tc;
}

// 256 blocks x 256 thr (4 waves), 1 block/CU. Block = 16 batches; wave w owns
// hidden strip n in [16w,16w+16) for ALL 4 gates. ZERO-WASTE decomposition:
// A rows = the 16 batches (all live, no time-packing) -> 8 xproj + 8 recurrent
// MFMA per wave/step = 310 cyc/SIMD matrix pipe (the true per-SIMD MFMA cost is
// ~19.4 cyc/instr; m06's 4.85 is per-CU); every lane activates 4 REAL states
// (no exec-masked issue waste). xproj is h-independent and issues first, hiding
// the h ds_read latency. h exchange: double-buffered [batch][n ^ ((batch>>2)<<4)]
// (writes spread over all 32 banks, reads 2-way aliased = free). wclf in LDS.
// One 4-wave barrier per step.
__global__ __launch_bounds__(256, 1)
void lstm_fm(const float* __restrict__ x, const float* __restrict__ w_ih,
             const float* __restrict__ w_hh, const float* __restrict__ b_ih,
             const float* __restrict__ b_hh, const float* __restrict__ w_clf,
             const float* __restrict__ b_clf, float* __restrict__ out) {
  extern __shared__ char smem[];
  float*    wclf  = (float*)smem;                       // [301][64], 77056 B
  ushort_t* hflat = (ushort_t*)(smem + 77056);          // [2][16][64], 4096 B
  float*    red   = (float*)(smem + 77056 + 4096);      // [4][16], 256 B

  const int tid = threadIdx.x;
  const int l   = tid & 63, w = tid >> 6;
  const int c15 = l & 15, g16 = l >> 4;
  const int n   = w * 16 + c15;            // this lane's D-col hidden index
  const int b0  = blockIdx.x * 16;
  const float gsc[4] = {LOG2E, LOG2E, 2.0f * LOG2E, LOG2E};

  // ---- stage wclf (f32, float4-vectorized) + zero h buffers ----
  for (int i = tid; i < (T_STEPS * 64) / 4; i += 256)
    ((float4*)wclf)[i] = ((const float4*)w_clf)[i];
  for (int i = tid; i < 1024; i += 256) ((uint_t*)hflat)[i] = 0;

  // ---- weights in registers (fp16, prescaled); bias via k=40 channel ----
  f16x8 whh[4][2], wih[4][2];
#pragma unroll
  for (int g = 0; g < 4; ++g) {
    const float s = gsc[g];
    const float* wr = w_hh + (size_t)(g * 64 + n) * 64;
#pragma unroll
    for (int kc = 0; kc < 2; ++kc) {
      float4 v0 = *(const float4*)(wr + kc * 32 + g16 * 8);
      float4 v1 = *(const float4*)(wr + kc * 32 + g16 * 8 + 4);
      v0.x *= s; v0.y *= s; v0.z *= s; v0.w *= s;
      v1.x *= s; v1.y *= s; v1.z *= s; v1.w *= s;
      whh[g][kc] = cvt8h(v0, v1);
    }
    const float* wi = w_ih + (size_t)(g * 64 + n) * IN_DIM;
    {
      float4 v0 = *(const float4*)(wi + g16 * 8);      // k = 8*g16..+7 <= 31
      float4 v1 = *(const float4*)(wi + g16 * 8 + 4);
      v0.x *= s; v0.y *= s; v0.z *= s; v0.w *= s;
      v1.x *= s; v1.y *= s; v1.z *= s; v1.w *= s;
      wih[g][0] = cvt8h(v0, v1);
    }
    {
      float4 u0 = make_float4(0, 0, 0, 0), u1 = make_float4(0, 0, 0, 0);
      if (g16 == 0) {                                  // k = 32..39
        u0 = *(const float4*)(wi + 32);
        u1 = *(const float4*)(wi + 36);
        u0.x *= s; u0.y *= s; u0.z *= s; u0.w *= s;
        u1.x *= s; u1.y *= s; u1.z *= s; u1.w *= s;
      } else if (g16 == 1) {                           // k = 40: bias row
        u0.x = (b_ih[g * 64 + n] + b_hh[g * 64 + n]) * s;
      }
      wih[g][1] = cvt8h(u0, u1);
    }
  }
  __syncthreads();   // staging visible

  // ---- loop-invariant LDS indices (ushort units) ----
  // A-read: row = batch = c15; k = kc*32 + 8*g16 + e; stored col = k ^ key(row)
  const int akey = (c15 >> 2) << 4;
  const int ridx0 = c15 * 64 + ((0 * 32 + 8 * g16) ^ akey);   // kc0, 16B-aligned
  const int ridx1 = c15 * 64 + ((1 * 32 + 8 * g16) ^ akey);   // kc1
  // D-write: batch = 4*g16 + r at col n, stored at n ^ (g16<<4)
  int widx[4];
#pragma unroll
  for (int r = 0; r < 4; ++r) widx[r] = (4 * g16 + r) * 64 + (n ^ (g16 << 4));

  // ---- x A-side: lane provides row (batch) c15, k = 8*g16.. ----
  const float* xb = x + (size_t)(b0 + c15) * T_STEPS * IN_DIM;
  float4 px0 = *(const float4*)(xb + g16 * 8);
  float4 px1 = *(const float4*)(xb + g16 * 8 + 4);
  float4 pq0 = make_float4(0, 0, 0, 0), pq1 = make_float4(0, 0, 0, 0);
  if (g16 == 0) {
    pq0 = *(const float4*)(xb + 32);
    pq1 = *(const float4*)(xb + 36);
  }
  f16x8 xf1c = {};                         // constant kc1 frag for g16 != 0
  if (g16 == 1) xf1c[0] = (_Float16)1.0f;  // k=40 bias multiplier

  f32x4 z[4];
  float cc[4]  = {0.f, 0.f, 0.f, 0.f};
  float acl[4] = {0.f, 0.f, 0.f, 0.f};

  for (int t = 0; t < T_STEPS; ++t) {
    const int rb = (t & 1) * 1024, wb = 1024 - rb;

    // issue h A-frag reads first; xproj below doesn't depend on them
    f16x8 a0 = *(const f16x8*)(hflat + rb + ridx0);
    f16x8 a1 = *(const f16x8*)(hflat + rb + ridx1);

    // xproj: z = x[t] @ wih^T (+bias via k=40) — full M=16, h-independent
    f16x8 xf0 = cvt8h(px0, px1);
    f16x8 xf1 = xf1c;
    if (g16 == 0) xf1 = cvt8h(pq0, pq1);
#pragma unroll
    for (int g = 0; g < 4; ++g) {
      f32x4 zz = {0.f, 0.f, 0.f, 0.f};
      zz = MFMA16(xf0, wih[g][0], zz);
      z[g] = MFMA16(xf1, wih[g][1], zz);
    }

    // prefetch next step's x (completes under this step's act phase)
    {
      const int tn = (t + 1 < T_STEPS) ? t + 1 : t;
      const float* xp = xb + (size_t)tn * IN_DIM;
      px0 = *(const float4*)(xp + g16 * 8);
      px1 = *(const float4*)(xp + g16 * 8 + 4);
      if (g16 == 0) {
        pq0 = *(const float4*)(xp + 32);
        pq1 = *(const float4*)(xp + 36);
      }
    }

    // recurrence: z += h[t-1] @ whh^T (waits on a0/a1 via compiler lgkmcnt)
#pragma unroll
    for (int g = 0; g < 4; ++g) {
      z[g] = MFMA16(a0, whh[g][0], z[g]);
      z[g] = MFMA16(a1, whh[g][1], z[g]);
    }

    // activations: 4 REAL states per lane (batches 4*g16+r at hidden n)
    const float wc = wclf[t * 64 + n];
#pragma unroll
    for (int r = 0; r < 4; ++r) {
      const float h = lstm_act(z[0][r], z[1][r], z[2][r], z[3][r], cc[r]);
      acl[r] += h * wc;
      u16cv cv; cv.hf = (_Float16)h;
      hflat[wb + widx[r]] = cv.u;
    }

    asm volatile("s_waitcnt lgkmcnt(0)\n\ts_barrier" ::: "memory");
  }

  // ---- epilogue: reduce acl over n (c15 lanes), then across waves ----
#pragma unroll
  for (int m = 1; m <= 8; m <<= 1) {
#pragma unroll
    for (int r = 0; r < 4; ++r) acl[r] += __shfl_xor(acl[r], m);
  }
  if (c15 == 0) {
#pragma unroll
    for (int r = 0; r < 4; ++r) red[w * 16 + 4 * g16 + r] = acl[r];
  }
  __syncthreads();
  if (tid < 16)
    out[b0 + tid] = b_clf[0] + red[tid] + red[16 + tid] + red[32 + tid] + red[48 + tid];
}

extern "C" void kernel_launch(void* const* d_in, const int* in_sizes, int n_in,
                              void* d_out, int out_size, void* d_ws, size_t ws_size,
                              hipStream_t stream) {
  const float* x     = (const float*)d_in[0];
  const float* w_ih  = (const float*)d_in[1];
  const float* w_hh  = (const float*)d_in[2];
  const float* b_ih  = (const float*)d_in[3];
  const float* b_hh  = (const float*)d_in[4];
  const float* w_clf = (const float*)d_in[5];
  const float* b_clf = (const float*)d_in[6];
  float* out = (float*)d_out;

  const size_t shmem = 77056 + 4096 + 256;   // ~79.5 KB dynamic LDS
  (void)hipFuncSetAttribute((const void*)lstm_fm,
                            hipFuncAttributeMaxDynamicSharedMemorySize, (int)shmem);
  lstm_fm<<<256, 256, shmem, stream>>>(x, w_ih, w_hh, b_ih, b_hh, w_clf, b_clf, out);
}

// Round 14
// 173.854 us; speedup vs baseline: 1.3954x; 1.0438x over previous
//
#include <hip/hip_runtime.h>

#define T_STEPS 301
#define IN_DIM  40
#define LOG2E   1.44269504088896340736f

typedef __attribute__((ext_vector_type(8))) _Float16 f16x8;
typedef __attribute__((ext_vector_type(4))) float f32x4;
typedef unsigned short ushort_t;
typedef unsigned int uint_t;

union u16cv { _Float16 hf; ushort_t u; };

#define MFMA16(A, B, C) __builtin_amdgcn_mfma_f32_16x16x32_f16((A), (B), (C), 0, 0, 0)

__device__ __forceinline__ f16x8 cvt8h(const float4 a, const float4 b) {
  f16x8 r;
  r[0] = (_Float16)a.x; r[1] = (_Float16)a.y; r[2] = (_Float16)a.z; r[3] = (_Float16)a.w;
  r[4] = (_Float16)b.x; r[5] = (_Float16)b.y; r[6] = (_Float16)b.z; r[7] = (_Float16)b.w;
  return r;
}

// z pre-scaled by log2e (2*log2e for g-gate) -> exp2-based activations.
__device__ __forceinline__ float lstm_act(float zi, float zf, float zg, float zo, float& cc) {
  const float ig = __builtin_amdgcn_rcpf(1.0f + __builtin_amdgcn_exp2f(-zi));
  const float fg = __builtin_amdgcn_rcpf(1.0f + __builtin_amdgcn_exp2f(-zf));
  const float gg = 1.0f - 2.0f * __builtin_amdgcn_rcpf(1.0f + __builtin_amdgcn_exp2f(zg));
  const float og = __builtin_amdgcn_rcpf(1.0f + __builtin_amdgcn_exp2f(-zo));
  cc = fg * cc + ig * gg;
  const float tc = 1.0f - 2.0f * __builtin_amdgcn_rcpf(1.0f + __builtin_amdgcn_exp2f(cc * (2.0f * LOG2E)));
  return og * tc;
}

// 256 blocks x 256 thr (4 waves), 1 block/CU, zero-waste M=16 (R13 base).
// R14: software-pipelined step. z/zn ping-pong (2-step unroll, static indexing):
//   barrier -> ds_read h -> rec MFMA(t) on z ->
//   [ xproj(t+1) MFMAs into zn + x cvt/prefetch  ||  act(t) transcendentals ] ->
//   write h -> barrier
// The xproj volley (16 MFMA + cvts) issues inside act's trans-unit stall
// shadows -> matrix pipe works during the 640-cyc trans stream instead of
// idling. Everything else identical to R13 (zero-waste rows, bias via k=40
// channel, wclf in LDS, XOR-swizzled h exchange).
__global__ __launch_bounds__(256, 1)
void lstm_pp(const float* __restrict__ x, const float* __restrict__ w_ih,
             const float* __restrict__ w_hh, const float* __restrict__ b_ih,
             const float* __restrict__ b_hh, const float* __restrict__ w_clf,
             const float* __restrict__ b_clf, float* __restrict__ out) {
  extern __shared__ char smem[];
  float*    wclf  = (float*)smem;                       // [301][64], 77056 B
  ushort_t* hflat = (ushort_t*)(smem + 77056);          // [2][16][64], 4096 B
  float*    red   = (float*)(smem + 77056 + 4096);      // [4][16], 256 B

  const int tid = threadIdx.x;
  const int l   = tid & 63, w = tid >> 6;
  const int c15 = l & 15, g16 = l >> 4;
  const int n   = w * 16 + c15;
  const int b0  = blockIdx.x * 16;
  const float gsc[4] = {LOG2E, LOG2E, 2.0f * LOG2E, LOG2E};

  for (int i = tid; i < (T_STEPS * 64) / 4; i += 256)
    ((float4*)wclf)[i] = ((const float4*)w_clf)[i];
  for (int i = tid; i < 1024; i += 256) ((uint_t*)hflat)[i] = 0;

  // ---- weights in registers (fp16, prescaled); bias via k=40 channel ----
  f16x8 whh[4][2], wih[4][2];
#pragma unroll
  for (int g = 0; g < 4; ++g) {
    const float s = gsc[g];
    const float* wr = w_hh + (size_t)(g * 64 + n) * 64;
#pragma unroll
    for (int kc = 0; kc < 2; ++kc) {
      float4 v0 = *(const float4*)(wr + kc * 32 + g16 * 8);
      float4 v1 = *(const float4*)(wr + kc * 32 + g16 * 8 + 4);
      v0.x *= s; v0.y *= s; v0.z *= s; v0.w *= s;
      v1.x *= s; v1.y *= s; v1.z *= s; v1.w *= s;
      whh[g][kc] = cvt8h(v0, v1);
    }
    const float* wi = w_ih + (size_t)(g * 64 + n) * IN_DIM;
    {
      float4 v0 = *(const float4*)(wi + g16 * 8);
      float4 v1 = *(const float4*)(wi + g16 * 8 + 4);
      v0.x *= s; v0.y *= s; v0.z *= s; v0.w *= s;
      v1.x *= s; v1.y *= s; v1.z *= s; v1.w *= s;
      wih[g][0] = cvt8h(v0, v1);
    }
    {
      float4 u0 = make_float4(0, 0, 0, 0), u1 = make_float4(0, 0, 0, 0);
      if (g16 == 0) {
        u0 = *(const float4*)(wi + 32);
        u1 = *(const float4*)(wi + 36);
        u0.x *= s; u0.y *= s; u0.z *= s; u0.w *= s;
        u1.x *= s; u1.y *= s; u1.z *= s; u1.w *= s;
      } else if (g16 == 1) {
        u0.x = (b_ih[g * 64 + n] + b_hh[g * 64 + n]) * s;   // k=40 bias row
      }
      wih[g][1] = cvt8h(u0, u1);
    }
  }
  __syncthreads();

  // loop-invariant LDS indices (R13 layout)
  const int akey = (c15 >> 2) << 4;
  const int ridx0 = c15 * 64 + ((0 * 32 + 8 * g16) ^ akey);
  const int ridx1 = c15 * 64 + ((1 * 32 + 8 * g16) ^ akey);
  int widx[4];
#pragma unroll
  for (int r = 0; r < 4; ++r) widx[r] = (4 * g16 + r) * 64 + (n ^ (g16 << 4));

  const float* xb = x + (size_t)(b0 + c15) * T_STEPS * IN_DIM;
  f16x8 xf1c = {};
  if (g16 == 1) xf1c[0] = (_Float16)1.0f;   // k=40 bias multiplier

  f32x4 z[4], zn[4];
  float cc[4]  = {0.f, 0.f, 0.f, 0.f};
  float acl[4] = {0.f, 0.f, 0.f, 0.f};

  // ---- prologue: xproj(t=0) directly into z; prefetch x[1] ----
  {
    const float4 v0 = *(const float4*)(xb + g16 * 8);
    const float4 v1 = *(const float4*)(xb + g16 * 8 + 4);
    f16x8 xf0 = cvt8h(v0, v1);
    f16x8 xf1 = xf1c;
    if (g16 == 0) {
      const float4 u0 = *(const float4*)(xb + 32);
      const float4 u1 = *(const float4*)(xb + 36);
      xf1 = cvt8h(u0, u1);
    }
#pragma unroll
    for (int g = 0; g < 4; ++g) {
      f32x4 zz = {0.f, 0.f, 0.f, 0.f};
      zz = MFMA16(xf0, wih[g][0], zz);
      z[g] = MFMA16(xf1, wih[g][1], zz);
    }
  }
  float4 px0, px1, pq0 = make_float4(0, 0, 0, 0), pq1 = make_float4(0, 0, 0, 0);
  {
    const float* xp = xb + IN_DIM;       // x[1]
    px0 = *(const float4*)(xp + g16 * 8);
    px1 = *(const float4*)(xp + g16 * 8 + 4);
    if (g16 == 0) {
      pq0 = *(const float4*)(xp + 32);
      pq1 = *(const float4*)(xp + 36);
    }
  }

  // STEP: rec(t) on ZC; act(t) from ZC interleaved with xproj(t+1) into ZN.
#define STEP(ZC, ZN, T, LAST)                                                     \
  {                                                                               \
    const int rb = ((T) & 1) * 1024, wb = 1024 - rb;                              \
    f16x8 a0 = *(const f16x8*)(hflat + rb + ridx0);                               \
    f16x8 a1 = *(const f16x8*)(hflat + rb + ridx1);                               \
    _Pragma("unroll")                                                             \
    for (int g = 0; g < 4; ++g) {                                                 \
      ZC[g] = MFMA16(a0, whh[g][0], ZC[g]);                                       \
      ZC[g] = MFMA16(a1, whh[g][1], ZC[g]);                                       \
    }                                                                             \
    if (!(LAST)) {                                                                \
      f16x8 xf0 = cvt8h(px0, px1);                                                \
      f16x8 xf1 = xf1c;                                                           \
      if (g16 == 0) xf1 = cvt8h(pq0, pq1);                                        \
      _Pragma("unroll")                                                           \
      for (int g = 0; g < 4; ++g) {                                               \
        f32x4 zz = {0.f, 0.f, 0.f, 0.f};                                          \
        zz = MFMA16(xf0, wih[g][0], zz);                                          \
        ZN[g] = MFMA16(xf1, wih[g][1], zz);                                       \
      }                                                                           \
      const int tn = ((T) + 2 < T_STEPS) ? (T) + 2 : T_STEPS - 1;                 \
      const float* xp = xb + (size_t)tn * IN_DIM;                                 \
      px0 = *(const float4*)(xp + g16 * 8);                                       \
      px1 = *(const float4*)(xp + g16 * 8 + 4);                                   \
      if (g16 == 0) {                                                             \
        pq0 = *(const float4*)(xp + 32);                                          \
        pq1 = *(const float4*)(xp + 36);                                          \
      }                                                                           \
    }                                                                             \
    const float wc = wclf[(T) * 64 + n];                                          \
    _Pragma("unroll")                                                             \
    for (int r = 0; r < 4; ++r) {                                                 \
      const float h = lstm_act(ZC[0][r], ZC[1][r], ZC[2][r], ZC[3][r], cc[r]);    \
      acl[r] += h * wc;                                                           \
      u16cv cv; cv.hf = (_Float16)h;                                              \
      hflat[wb + widx[r]] = cv.u;                                                 \
    }                                                                             \
    asm volatile("s_waitcnt lgkmcnt(0)\n\ts_barrier" ::: "memory");               \
  }

  for (int p = 0; p < 150; ++p) {
    const int t0 = 2 * p;
    STEP(z, zn, t0, 0)
    STEP(zn, z, t0 + 1, 0)
  }
  STEP(z, zn, 300, 1)
#undef STEP

  // ---- epilogue: reduce acl over c15 lanes, then across waves ----
#pragma unroll
  for (int m = 1; m <= 8; m <<= 1) {
#pragma unroll
    for (int r = 0; r < 4; ++r) acl[r] += __shfl_xor(acl[r], m);
  }
  if (c15 == 0) {
#pragma unroll
    for (int r = 0; r < 4; ++r) red[w * 16 + 4 * g16 + r] = acl[r];
  }
  __syncthreads();
  if (tid < 16)
    out[b0 + tid] = b_clf[0] + red[tid] + red[16 + tid] + red[32 + tid] + red[48 + tid];
}

extern "C" void kernel_launch(void* const* d_in, const int* in_sizes, int n_in,
                              void* d_out, int out_size, void* d_ws, size_t ws_size,
                              hipStream_t stream) {
  const float* x     = (const float*)d_in[0];
  const float* w_ih  = (const float*)d_in[1];
  const float* w_hh  = (const float*)d_in[2];
  const float* b_ih  = (const float*)d_in[3];
  const float* b_hh  = (const float*)d_in[4];
  const float* w_clf = (const float*)d_in[5];
  const float* b_clf = (const float*)d_in[6];
  float* out = (float*)d_out;

  const size_t shmem = 77056 + 4096 + 256;   // ~79.5 KB dynamic LDS
  (void)hipFuncSetAttribute((const void*)lstm_pp,
                            hipFuncAttributeMaxDynamicSharedMemorySize, (int)shmem);
  lstm_pp<<<256, 256, shmem, stream>>>(x, w_ih, w_hh, b_ih, b_hh, w_clf, b_clf, out);
}